// Round 4
// baseline (129.637 us; speedup 1.0000x reference)
//
#include <hip/hip_runtime.h>
#include <stdint.h>

#define B 4096
#define D 2048
#define BK 128          // k-slab per K-step (fp8 elements; 128 B rows)
#define NITER (D / BK)  // 16
#define BM 64
#define BN 128

typedef unsigned long long ull;
typedef float f32x4 __attribute__((ext_vector_type(4)));
typedef long v2l __attribute__((ext_vector_type(2)));  // 16 B, 16-B aligned

#define SENT_P 0x00000000FFFFFFFFull  // dist=0.0, ~idx -> "no positive seen"
#define SENT_N (~0ull)                // +inf      -> "no negative seen"

// ---------------- async global->LDS (16B per lane, wave-uniform LDS base) ----
__device__ __forceinline__ void async_copy16(const unsigned char* g, unsigned char* l) {
  __builtin_amdgcn_global_load_lds(
      (const __attribute__((address_space(1))) unsigned int*)g,
      (__attribute__((address_space(3))) unsigned int*)l,
      16, 0, 0);
}

// ---------------- fp32 -> fp8 e4m3 (OCP, RNE) + norms + sentinel init -------
// embq is written in a k-PERMUTED layout (dot products are invariant under a
// uniform k-permutation of both operands). Within each 128 B K-step segment:
//   orig k = s*32 + qp*8 + b  (s=slab 0..3, qp=MFMA lane-group 0..3, b=0..7)
//   stored at pos = qp*32 + s*8 + b   ("q-major")
// so one 16 B chunk c = qp*2 + (s>>1) holds a lane-group's fragments for TWO
// consecutive slabs -> the GEMM reads it with a single ds_read_b128.
__global__ void k_convert_sq(const float* __restrict__ emb,
                             unsigned char* __restrict__ embq,
                             float* __restrict__ sq,
                             float* __restrict__ rs,
                             ull* __restrict__ bp,
                             ull* __restrict__ bn,
                             float* __restrict__ red_sum,
                             int* __restrict__ red_cnt,
                             int* __restrict__ red_done) {
  const int row = blockIdx.x, t = threadIdx.x;
  const float4* src = (const float4*)(emb + (size_t)row * D);
  float4 v0 = src[2 * t], v1 = src[2 * t + 1];
  float s = v0.x * v0.x + v0.y * v0.y + v0.z * v0.z + v0.w * v0.w
          + v1.x * v1.x + v1.y * v1.y + v1.z * v1.z + v1.w * v1.w;
  float sm = v0.x + v0.y + v0.z + v0.w + v1.x + v1.y + v1.z + v1.w;

  unsigned w0 = __builtin_amdgcn_cvt_pk_fp8_f32(v0.x, v0.y, 0, false);
  w0 = __builtin_amdgcn_cvt_pk_fp8_f32(v0.z, v0.w, w0, true);
  unsigned w1 = __builtin_amdgcn_cvt_pk_fp8_f32(v1.x, v1.y, 0, false);
  w1 = __builtin_amdgcn_cvt_pk_fp8_f32(v1.z, v1.w, w1, true);
  uint2 o; o.x = w0; o.y = w1;
  // thread t holds orig k in [8t, 8t+8): kb = t>>4, s = (t>>2)&3, qp = t&3
  const int pos = ((t >> 4) << 7) | ((t & 3) << 5) | (((t >> 2) & 3) << 3);
  *(uint2*)(embq + (size_t)row * D + pos) = o;

  for (int off = 32; off; off >>= 1) {
    s  += __shfl_down(s, off, 64);
    sm += __shfl_down(sm, off, 64);
  }
  __shared__ float ps[4], pm[4];
  int lane = t & 63, wave = t >> 6;
  if (lane == 0) { ps[wave] = s; pm[wave] = sm; }
  __syncthreads();
  if (t == 0) {
    sq[row] = ps[0] + ps[1] + ps[2] + ps[3];
    rs[row] = pm[0] + pm[1] + pm[2] + pm[3];
    bp[row] = SENT_P;
    bn[row] = SENT_N;
    if (row == 0) { *red_sum = 0.0f; *red_cnt = 0; *red_done = 0; }
  }
}

// ---------------- fused symmetric fp8 GEMM + hard pos/neg selection ---------
// 64x128 block tiles over the strict upper triangle (1056 blocks, proven
// sequential triangular decode), single-buffered 24 KB LDS (6 blocks/CU),
// __syncthreads drain per K-step, q-major k-permuted embq so every fragment
// fetch is one ds_read_b128 serving two k-slabs at the b128 bank floor.
// Round-4 change: 2 waves/block, each owning a 64x64 output (4x4 fragment
// grid) -> 32 b128 reads per block-K-step instead of 48 (-33% LDS read
// traffic, the largest per-CU pipe load), same MFMA work, 12 waves/CU.
__launch_bounds__(128, 3)
__global__ void k_gemm_select(const unsigned char* __restrict__ embq,
                              const float* __restrict__ sq,
                              const int* __restrict__ labels,
                              ull* __restrict__ best_pos,
                              ull* __restrict__ best_neg) {
  __shared__ __align__(16) unsigned char ldsA[BM * BK];  // 8 KB
  __shared__ __align__(16) unsigned char ldsB[BN * BK];  // 16 KB

  // linear bid -> (by in [0,64), bx in [0,32)) with bx*128+127 > by*64
  int rem = blockIdx.x, p = 0;
  while (rem >= 2 * (32 - p)) { rem -= 2 * (32 - p); ++p; }
  int by = 2 * p;
  int c = 32 - p;
  if (rem >= c) { by += 1; rem -= c; }
  const int bx = p + rem;

  const int tid  = threadIdx.x;
  const int lane = tid & 63;
  const int wave = tid >> 6;              // 0 or 1: column half of the B tile
  const int q = lane >> 4, m15 = lane & 15;
  const int ibase = by * BM, jbase = bx * BN;

  // b128 fragment read offsets for slab-pair sh (slabs 2sh, 2sh+1), group g:
  //   row = base + g*16 + m15 ; chunk = q*2 + sh ; slot = chunk ^ (row&7)
  //   byte = row*128 + slot*16   (16-B aligned; [0,8)=slab 2sh, [8,16)=2sh+1)
  int aoff[2][4], boff[2][4];
#pragma unroll
  for (int sh = 0; sh < 2; ++sh) {
#pragma unroll
    for (int g = 0; g < 4; ++g) {
      int ra = g * 16 + m15;
      aoff[sh][g] = ra * BK + (((q * 2 + sh) ^ (ra & 7)) * 16);
      int rb = wave * 64 + g * 16 + m15;
      boff[sh][g] = rb * BK + (((q * 2 + sh) ^ (rb & 7)) * 16);
    }
  }

  // staging: 12 issues/wave per K-step (4 A + 8 B), 8 rows x 1 KB per issue.
  // LDS dest linear (base + lane*16); global source pre-swizzled so LDS slot
  // `slot` holds global chunk slot^(row&7)  (XOR involution matches reads).
  const int srow = lane >> 3;  // row within 8-row staging group
  const int slot = lane & 7;   // 16B slot within 128B row
  size_t agoff[4], bgoff[8];
  int lasta[4], lastb[8];
#pragma unroll
  for (int pp = 0; pp < 4; ++pp) {
    int r0  = wave * 32 + pp * 8;  // wave-uniform
    int row = r0 + srow;
    agoff[pp] = (size_t)(ibase + row) * D + (slot ^ (row & 7)) * 16;
    lasta[pp] = r0 * BK;
  }
#pragma unroll
  for (int pp = 0; pp < 8; ++pp) {
    int r0  = wave * 64 + pp * 8;  // wave-uniform
    int row = r0 + srow;
    bgoff[pp] = (size_t)(jbase + row) * D + (slot ^ (row & 7)) * 16;
    lastb[pp] = r0 * BK;
  }

  f32x4 acc[4][4];
  const f32x4 z = {0.f, 0.f, 0.f, 0.f};
#pragma unroll
  for (int a = 0; a < 4; ++a)
#pragma unroll
    for (int b = 0; b < 4; ++b) acc[a][b] = z;

  for (int kb = 0; kb < D; kb += BK) {
    __syncthreads();
#pragma unroll
    for (int pp = 0; pp < 4; ++pp)
      async_copy16(embq + agoff[pp] + kb, &ldsA[lasta[pp]]);
#pragma unroll
    for (int pp = 0; pp < 8; ++pp)
      async_copy16(embq + bgoff[pp] + kb, &ldsB[lastb[pp]]);
    __syncthreads();  // compiler emits vmcnt(0) drain before barrier

#pragma unroll
    for (int sh = 0; sh < 2; ++sh) {
      v2l af[4], bf[4];
#pragma unroll
      for (int g = 0; g < 4; ++g) af[g] = *(const v2l*)&ldsA[aoff[sh][g]];
#pragma unroll
      for (int g = 0; g < 4; ++g) bf[g] = *(const v2l*)&ldsB[boff[sh][g]];
#pragma unroll
      for (int mi = 0; mi < 4; ++mi)
#pragma unroll
        for (int ni = 0; ni < 4; ++ni)
          acc[mi][ni] = __builtin_amdgcn_mfma_f32_16x16x32_fp8_fp8(
              af[mi][0], bf[ni][0], acc[mi][ni], 0, 0, 0);
#pragma unroll
      for (int mi = 0; mi < 4; ++mi)
#pragma unroll
        for (int ni = 0; ni < 4; ++ni)
          acc[mi][ni] = __builtin_amdgcn_mfma_f32_16x16x32_fp8_fp8(
              af[mi][1], bf[ni][1], acc[mi][ni], 0, 0, 0);
    }
  }

  // ---- epilogue ----
  float sqj[4];
  int labj[4];
#pragma unroll
  for (int ni = 0; ni < 4; ++ni) {
    int jj = jbase + wave * 64 + ni * 16 + m15;
    sqj[ni] = sq[jj];
    labj[ni] = labels[jj];
  }

  ull colBp[4], colBn[4];
#pragma unroll
  for (int ni = 0; ni < 4; ++ni) { colBp[ni] = SENT_P; colBn[ni] = SENT_N; }

#pragma unroll
  for (int mi = 0; mi < 4; ++mi) {
#pragma unroll
    for (int r = 0; r < 4; ++r) {
      const int i = ibase + mi * 16 + q * 4 + r;   // C/D row=(lane>>4)*4+r
      const float si = sq[i];
      const int li = labels[i];
      ull bp = SENT_P;
      ull bn = SENT_N;
#pragma unroll
      for (int ni = 0; ni < 4; ++ni) {
        int jj = jbase + wave * 64 + ni * 16 + m15;  // C/D col=lane&15
        if (jj > i) {                                // strict upper triangle
          float dot = acc[mi][ni][r];
          float d2 = si + sqj[ni] - 2.0f * dot;
          float dist = sqrtf(fmaxf(d2, 0.0f));
          ull pv = ((ull)__float_as_uint(dist)) << 32;
          if (labj[ni] == li) {
            ull cr = pv | (unsigned)(~jj);  // max -> smallest idx wins ties
            bp = bp > cr ? bp : cr;
            ull cc = pv | (unsigned)(~i);
            colBp[ni] = colBp[ni] > cc ? colBp[ni] : cc;
          } else {
            ull cr = pv | (unsigned)jj;     // min -> smallest idx wins ties
            bn = bn < cr ? bn : cr;
            ull cc = pv | (unsigned)i;
            colBn[ni] = colBn[ni] < cc ? colBn[ni] : cc;
          }
        }
      }
      // row-i reduction across the 16 column lanes (m15 bits)
#pragma unroll
      for (int off = 1; off <= 8; off <<= 1) {
        ull op = __shfl_xor(bp, off, 64);
        ull on = __shfl_xor(bn, off, 64);
        bp = bp > op ? bp : op;
        bn = bn < on ? bn : on;
      }
      if (m15 == 0) {
        if (bp != SENT_P) atomicMax(&best_pos[i], bp);
        if (bn != SENT_N) atomicMin(&best_neg[i], bn);
      }
    }
  }

  // col-j reduction across the 4 q lane-groups
#pragma unroll
  for (int ni = 0; ni < 4; ++ni) {
    ull cp = colBp[ni], cn = colBn[ni];
#pragma unroll
    for (int off = 16; off <= 32; off <<= 1) {
      ull op = __shfl_xor(cp, off, 64);
      ull on = __shfl_xor(cn, off, 64);
      cp = cp > op ? cp : op;
      cn = cn < on ? cn : on;
    }
    if (q == 0) {
      int j = jbase + wave * 64 + ni * 16 + m15;
      if (cp != SENT_P) atomicMax(&best_pos[j], cp);
      if (cn != SENT_N) atomicMin(&best_neg[j], cn);
    }
  }
}

// ---------------- loss: 16-block partial reduce, last block finalizes -------
// Each block handles 256 anchors (one per thread), reduces per+valid to one
// atomicAdd pair, then bumps a done-counter; the 16th arrival re-reads the
// device-scope accumulators (all prior adds ordered by threadfence before the
// counter bump) and writes the final mean. Removes the single-block serial
// latency chain of the old k_loss_final.
__global__ void k_loss_final(const ull* __restrict__ best_pos,
                             const ull* __restrict__ best_neg,
                             const float* __restrict__ rs,
                             float* __restrict__ red_sum,
                             int* __restrict__ red_cnt,
                             int* __restrict__ red_done,
                             float* __restrict__ out) {
  const int i = blockIdx.x * 256 + threadIdx.x;
  float per = 0.0f;
  int v = 0;
  ull bp = best_pos[i], bn = best_neg[i];
  if (bp != SENT_P && bn != SENT_N) {
    unsigned pRaw = ~(unsigned)bp;
    unsigned nRaw = (unsigned)bn;
    int pi = pRaw < (unsigned)B ? (int)pRaw : 0;
    int ni = nRaw < (unsigned)B ? (int)nRaw : 0;
    float distp = __uint_as_float((unsigned)(bp >> 32));
    float distn = __uint_as_float((unsigned)(bn >> 32));
    float ri = rs[i];
    const float e = 1e-6f, de2 = (float)D * 1e-12f;
    float dp2 = distp * distp + 2.0f * e * (ri - rs[pi]) + de2;
    float dn2 = distn * distn + 2.0f * e * (ri - rs[ni]) + de2;
    float dp = sqrtf(fmaxf(dp2, 0.0f));
    float dn = sqrtf(fmaxf(dn2, 0.0f));
    per = fmaxf(dp - dn + 0.3f, 0.0f);
    v = 1;
  }
  for (int off = 32; off; off >>= 1) {
    per += __shfl_down(per, off, 64);
    v   += __shfl_down(v, off, 64);
  }
  __shared__ float pps[4];
  __shared__ int pvs[4];
  int lane = threadIdx.x & 63, wave = threadIdx.x >> 6;
  if (lane == 0) { pps[wave] = per; pvs[wave] = v; }
  __syncthreads();
  if (threadIdx.x == 0) {
    float t = pps[0] + pps[1] + pps[2] + pps[3];
    int cv = pvs[0] + pvs[1] + pvs[2] + pvs[3];
    atomicAdd(red_sum, t);
    atomicAdd(red_cnt, cv);
    __threadfence();
    int old = atomicAdd(red_done, 1);
    if (old == (int)gridDim.x - 1) {
      float s = atomicAdd(red_sum, 0.0f);   // coherent device-scope read
      int cc = atomicAdd(red_cnt, 0);
      out[0] = cc > 0 ? s / (float)cc : 0.0f;
    }
  }
}

// ---------------- launch -----------------------------------------------------
extern "C" void kernel_launch(void* const* d_in, const int* in_sizes, int n_in,
                              void* d_out, int out_size, void* d_ws, size_t ws_size,
                              hipStream_t stream) {
  const float* emb = (const float*)d_in[0];
  const int* labels = (const int*)d_in[1];
  float* out = (float*)d_out;
  char* ws = (char*)d_ws;

  const size_t off_embq = 0;
  const size_t off_sq   = off_embq + (size_t)B * D;       // 8 MiB
  const size_t off_rs   = off_sq + (size_t)B * 4;
  const size_t off_bp   = off_rs + (size_t)B * 4;
  const size_t off_bn   = off_bp + (size_t)B * 8;
  const size_t off_red  = off_bn + (size_t)B * 8;

  unsigned char* embq = (unsigned char*)(ws + off_embq);
  float* sq   = (float*)(ws + off_sq);
  float* rs   = (float*)(ws + off_rs);
  ull* bp     = (ull*)(ws + off_bp);
  ull* bn     = (ull*)(ws + off_bn);
  float* red_sum = (float*)(ws + off_red);
  int* red_cnt   = (int*)(ws + off_red + 4);
  int* red_done  = (int*)(ws + off_red + 8);

  hipLaunchKernelGGL(k_convert_sq, dim3(B), dim3(256), 0, stream,
                     emb, embq, sq, rs, bp, bn, red_sum, red_cnt, red_done);
  hipLaunchKernelGGL(k_gemm_select, dim3(1056), dim3(128), 0, stream,
                     embq, sq, labels, bp, bn);
  hipLaunchKernelGGL(k_loss_final, dim3(B / 256), dim3(256), 0, stream,
                     bp, bn, rs, red_sum, red_cnt, red_done, out);
}